// Round 4
// baseline (160.585 us; speedup 1.0000x reference)
//
#include <hip/hip_runtime.h>

#define HSZ   16
#define TLEN  512
#define LOG2E 1.4426950408889634f

// ws layout (floats): [0..1023] scaled W_hh [64][16]; [1024..1087] scaled W_ih; [1088..1151] scaled (b_ih+b_hh)
__global__ __launch_bounds__(64) void prep_kernel(
    const float* __restrict__ W_ih, const float* __restrict__ W_hh,
    const float* __restrict__ b_ih, const float* __restrict__ b_hh,
    float* __restrict__ ws)
{
    const int r = threadIdx.x;  // 0..63 gate row, torch order i,f,g,o
    const float s = (r >= 32 && r < 48) ? (-2.0f * LOG2E) : (-LOG2E);  // tanh rows get -2*log2e
    #pragma unroll
    for (int k = 0; k < HSZ; ++k) ws[r * HSZ + k] = s * W_hh[r * HSZ + k];
    ws[1024 + r] = s * W_ih[r];
    ws[1088 + r] = s * (b_ih[r] + b_hh[r]);
}

// 4 batches per wave: 2 per 32-lane group, as two independent register streams (ILP to hide
// the serial-recurrence latency). Lane ll owns gate rows ll (i|f) and 32+ll (g|o) for BOTH
// of its group's batches (weights shared). c_j, h_j live in lane 16+j of the group.
// h broadcast via per-stream LDS buffer; block = 1 wave, so wave-synchronous (no barrier).
__global__ __launch_bounds__(64) void lstm_kernel(
    const float* __restrict__ x, const float* __restrict__ ws,
    const float* __restrict__ W_lin, float* __restrict__ out)
{
    __shared__ __align__(16) float xs[4 * TLEN];
    __shared__ __align__(16) float hbuf[4][HSZ];

    const int tid = threadIdx.x;
    const int g   = tid >> 5;   // group within wave (0,1); handles batches base+2g, base+2g+1
    const int ll  = tid & 31;   // lane within group
    const int j   = ll & 15;    // hidden index

    // stage x for all 4 batches (coalesced float4)
    {
        const float4* xv  = (const float4*)(x + (long)blockIdx.x * (4 * TLEN));
        float4*       xsv = (float4*)xs;
        #pragma unroll
        for (int i = 0; i < 8; ++i) xsv[i * 64 + tid] = xv[i * 64 + tid];
    }
    ((float*)hbuf)[tid] = 0.0f;
    __syncthreads();

    // per-lane weights (scaled): row rA = ll (sigmoid), row rB = 32+ll (tanh for ll<16, sigmoid for ll>=16)
    const int rA = ll;
    const int rB = 32 + ll;
    float4 wA[4], wB[4];
    #pragma unroll
    for (int q = 0; q < 4; ++q) {
        wA[q] = *(const float4*)(ws + rA * HSZ + 4 * q);
        wB[q] = *(const float4*)(ws + rB * HSZ + 4 * q);
    }
    const float wihA = ws[1024 + rA], wihB = ws[1024 + rB];
    const float bbA  = ws[1088 + rA], bbB  = ws[1088 + rB];
    const float mulB = (ll < 16) ? 2.0f : 1.0f;   // tanh = 2*sig(2x)-1
    const float addB = (ll < 16) ? -1.0f : 0.0f;

    const float* xg0 = xs + (2 * g + 0) * TLEN;
    const float* xg1 = xs + (2 * g + 1) * TLEN;
    float* hg0 = hbuf[2 * g + 0];
    float* hg1 = hbuf[2 * g + 1];

    float c0s = 0.0f, h0s = 0.0f;   // stream 0 state
    float c1s = 0.0f, h1s = 0.0f;   // stream 1 state

    for (int t = 0; t < TLEN; ++t) {
        const float xt0 = xg0[t];
        const float xt1 = xg1[t];
        const float4 p00 = *(const float4*)(hg0 + 0);
        const float4 p01 = *(const float4*)(hg0 + 4);
        const float4 p02 = *(const float4*)(hg0 + 8);
        const float4 p03 = *(const float4*)(hg0 + 12);
        const float4 p10 = *(const float4*)(hg1 + 0);
        const float4 p11 = *(const float4*)(hg1 + 4);
        const float4 p12 = *(const float4*)(hg1 + 8);
        const float4 p13 = *(const float4*)(hg1 + 12);

        // ---- stream 0 gate pre-activations ----
        float a0 = fmaf(xt0, wihA, bbA);
        float b0 = fmaf(xt0, wihB, bbB);
        float a1 = 0.0f, b1 = 0.0f;
        a0 = fmaf(p00.x, wA[0].x, a0);  a1 = fmaf(p00.y, wA[0].y, a1);
        a0 = fmaf(p00.z, wA[0].z, a0);  a1 = fmaf(p00.w, wA[0].w, a1);
        a0 = fmaf(p01.x, wA[1].x, a0);  a1 = fmaf(p01.y, wA[1].y, a1);
        a0 = fmaf(p01.z, wA[1].z, a0);  a1 = fmaf(p01.w, wA[1].w, a1);
        a0 = fmaf(p02.x, wA[2].x, a0);  a1 = fmaf(p02.y, wA[2].y, a1);
        a0 = fmaf(p02.z, wA[2].z, a0);  a1 = fmaf(p02.w, wA[2].w, a1);
        a0 = fmaf(p03.x, wA[3].x, a0);  a1 = fmaf(p03.y, wA[3].y, a1);
        a0 = fmaf(p03.z, wA[3].z, a0);  a1 = fmaf(p03.w, wA[3].w, a1);
        b0 = fmaf(p00.x, wB[0].x, b0);  b1 = fmaf(p00.y, wB[0].y, b1);
        b0 = fmaf(p00.z, wB[0].z, b0);  b1 = fmaf(p00.w, wB[0].w, b1);
        b0 = fmaf(p01.x, wB[1].x, b0);  b1 = fmaf(p01.y, wB[1].y, b1);
        b0 = fmaf(p01.z, wB[1].z, b0);  b1 = fmaf(p01.w, wB[1].w, b1);
        b0 = fmaf(p02.x, wB[2].x, b0);  b1 = fmaf(p02.y, wB[2].y, b1);
        b0 = fmaf(p02.z, wB[2].z, b0);  b1 = fmaf(p02.w, wB[2].w, b1);
        b0 = fmaf(p03.x, wB[3].x, b0);  b1 = fmaf(p03.y, wB[3].y, b1);
        b0 = fmaf(p03.z, wB[3].z, b0);  b1 = fmaf(p03.w, wB[3].w, b1);

        // ---- stream 1 gate pre-activations ----
        float e0 = fmaf(xt1, wihA, bbA);
        float f0 = fmaf(xt1, wihB, bbB);
        float e1 = 0.0f, f1 = 0.0f;
        e0 = fmaf(p10.x, wA[0].x, e0);  e1 = fmaf(p10.y, wA[0].y, e1);
        e0 = fmaf(p10.z, wA[0].z, e0);  e1 = fmaf(p10.w, wA[0].w, e1);
        e0 = fmaf(p11.x, wA[1].x, e0);  e1 = fmaf(p11.y, wA[1].y, e1);
        e0 = fmaf(p11.z, wA[1].z, e0);  e1 = fmaf(p11.w, wA[1].w, e1);
        e0 = fmaf(p12.x, wA[2].x, e0);  e1 = fmaf(p12.y, wA[2].y, e1);
        e0 = fmaf(p12.z, wA[2].z, e0);  e1 = fmaf(p12.w, wA[2].w, e1);
        e0 = fmaf(p13.x, wA[3].x, e0);  e1 = fmaf(p13.y, wA[3].y, e1);
        e0 = fmaf(p13.z, wA[3].z, e0);  e1 = fmaf(p13.w, wA[3].w, e1);
        f0 = fmaf(p10.x, wB[0].x, f0);  f1 = fmaf(p10.y, wB[0].y, f1);
        f0 = fmaf(p10.z, wB[0].z, f0);  f1 = fmaf(p10.w, wB[0].w, f1);
        f0 = fmaf(p11.x, wB[1].x, f0);  f1 = fmaf(p11.y, wB[1].y, f1);
        f0 = fmaf(p11.z, wB[1].z, f0);  f1 = fmaf(p11.w, wB[1].w, f1);
        f0 = fmaf(p12.x, wB[2].x, f0);  f1 = fmaf(p12.y, wB[2].y, f1);
        f0 = fmaf(p12.z, wB[2].z, f0);  f1 = fmaf(p12.w, wB[2].w, f1);
        f0 = fmaf(p13.x, wB[3].x, f0);  f1 = fmaf(p13.y, wB[3].y, f1);
        f0 = fmaf(p13.z, wB[3].z, f0);  f1 = fmaf(p13.w, wB[3].w, f1);

        // ---- stream 0 activations + state ----
        {
            const float accA = a0 + a1;
            const float accB = b0 + b1;
            const float sA   = __builtin_amdgcn_rcpf(1.0f + __builtin_amdgcn_exp2f(accA));
            const float sB   = __builtin_amdgcn_rcpf(1.0f + __builtin_amdgcn_exp2f(accB));
            const float actB = fmaf(mulB, sB, addB);                 // tanh(g) | o
            const float p    = sA * actB;                            // i*tanh(g) (lanes<16)
            const float v1   = __shfl_xor((ll < 16) ? p : sA, 16);
            c0s = fmaf(sA, c0s, v1);                                 // f*c + i*g (lanes>=16)
            const float u  = __builtin_amdgcn_exp2f(c0s * (-2.0f * LOG2E));
            const float th = fmaf(2.0f, __builtin_amdgcn_rcpf(1.0f + u), -1.0f);
            h0s = actB * th;                                         // o*tanh(c)
        }
        // ---- stream 1 activations + state ----
        {
            const float accA = e0 + e1;
            const float accB = f0 + f1;
            const float sA   = __builtin_amdgcn_rcpf(1.0f + __builtin_amdgcn_exp2f(accA));
            const float sB   = __builtin_amdgcn_rcpf(1.0f + __builtin_amdgcn_exp2f(accB));
            const float actB = fmaf(mulB, sB, addB);
            const float p    = sA * actB;
            const float v1   = __shfl_xor((ll < 16) ? p : sA, 16);
            c1s = fmaf(sA, c1s, v1);
            const float u  = __builtin_amdgcn_exp2f(c1s * (-2.0f * LOG2E));
            const float th = fmaf(2.0f, __builtin_amdgcn_rcpf(1.0f + u), -1.0f);
            h1s = actB * th;
        }

        __builtin_amdgcn_wave_barrier();
        if (ll >= 16) { hg0[j] = h0s; hg1[j] = h1s; }   // publish h for next step
        __builtin_amdgcn_wave_barrier();
    }

    // out[b] = sum_j h_j * W_lin[j]; valid h lives in lanes 16..31 of each group
    const float wl = W_lin[j];
    float v0 = h0s * wl;
    float v1 = h1s * wl;
    v0 += __shfl_xor(v0, 1);  v1 += __shfl_xor(v1, 1);
    v0 += __shfl_xor(v0, 2);  v1 += __shfl_xor(v1, 2);
    v0 += __shfl_xor(v0, 4);  v1 += __shfl_xor(v1, 4);
    v0 += __shfl_xor(v0, 8);  v1 += __shfl_xor(v1, 8);
    if (ll == 16) {
        out[blockIdx.x * 4 + 2 * g + 0] = v0;
        out[blockIdx.x * 4 + 2 * g + 1] = v1;
    }
}

extern "C" void kernel_launch(void* const* d_in, const int* in_sizes, int n_in,
                              void* d_out, int out_size, void* d_ws, size_t ws_size,
                              hipStream_t stream) {
    const float* x     = (const float*)d_in[0];
    const float* W_ih  = (const float*)d_in[1];
    const float* W_hh  = (const float*)d_in[2];
    const float* b_ih  = (const float*)d_in[3];
    const float* b_hh  = (const float*)d_in[4];
    const float* W_lin = (const float*)d_in[5];
    float* out = (float*)d_out;
    float* ws  = (float*)d_ws;

    const int B = in_sizes[0] / TLEN;  // 4096

    hipLaunchKernelGGL(prep_kernel, dim3(1), dim3(64), 0, stream,
                       W_ih, W_hh, b_ih, b_hh, ws);
    hipLaunchKernelGGL(lstm_kernel, dim3(B / 4), dim3(64), 0, stream,
                       x, ws, W_lin, out);
}

// Round 5
// 145.098 us; speedup vs baseline: 1.1067x; 1.1067x over previous
//
#include <hip/hip_runtime.h>

#define HSZ   16
#define TLEN  512
#define LOG2E 1.4426950408889634f

// ws layout (floats): [0..1023] scaled W_hh [64][16]; [1024..1087] scaled W_ih; [1088..1151] scaled (b_ih+b_hh)
__global__ __launch_bounds__(64) void prep_kernel(
    const float* __restrict__ W_ih, const float* __restrict__ W_hh,
    const float* __restrict__ b_ih, const float* __restrict__ b_hh,
    float* __restrict__ ws)
{
    const int r = threadIdx.x;  // 0..63 gate row, torch order i,f,g,o
    const float s = (r >= 32 && r < 48) ? (-2.0f * LOG2E) : (-LOG2E);  // tanh rows get -2*log2e
    #pragma unroll
    for (int k = 0; k < HSZ; ++k) ws[r * HSZ + k] = s * W_hh[r * HSZ + k];
    ws[1024 + r] = s * W_ih[r];
    ws[1088 + r] = s * (b_ih[r] + b_hh[r]);
}

// 16 lanes per batch element; lane j owns gate rows {j, 16+j, 32+j, 48+j} = (i,f,g,o)_j
// plus c_j, h_j. Gate math and the c/h update are fully lane-local; the only cross-lane
// op is the h broadcast: 15 independent __shfl_xor(h, m) (m<16 stays within the 16-lane
// group), paired with XOR-permuted weights W[r][j^m]. 4 batches per wave, 1 wave/block.
__global__ __launch_bounds__(64) void lstm_kernel(
    const float* __restrict__ x, const float* __restrict__ ws,
    const float* __restrict__ W_lin, float* __restrict__ out)
{
    __shared__ __align__(16) float xs[4][TLEN + 8];  // +8 pad: per-step 4-addr read hits banks {0,8,16,24}

    const int tid = threadIdx.x;
    const int g   = tid >> 4;   // batch slot within wave (0..3)
    const int j   = tid & 15;   // hidden index / lane within group

    // stage x for 4 batches (coalesced float4)
    {
        const float4* xv = (const float4*)(x + (long)blockIdx.x * (4 * TLEN));
        #pragma unroll
        for (int b = 0; b < 4; ++b) {
            float4* dst = (float4*)(&xs[b][0]);
            #pragma unroll
            for (int i = 0; i < 2; ++i)
                dst[i * 64 + tid] = xv[b * 128 + i * 64 + tid];
        }
    }
    __syncthreads();

    // preload XOR-permuted scaled weights: term m pairs __shfl_xor(h,m)=h_{j^m} with W[row][j^m]
    float w0[16], w1[16], w2[16], w3[16];
    #pragma unroll
    for (int m = 0; m < 16; ++m) {
        const int k = j ^ m;
        w0[m] = ws[(     j) * HSZ + k];   // i row
        w1[m] = ws[(16 + j) * HSZ + k];   // f row
        w2[m] = ws[(32 + j) * HSZ + k];   // g row (scaled -2log2e)
        w3[m] = ws[(48 + j) * HSZ + k];   // o row
    }
    const float wi0 = ws[1024 + j],      wi1 = ws[1024 + 16 + j];
    const float wi2 = ws[1024 + 32 + j], wi3 = ws[1024 + 48 + j];
    const float bb0 = ws[1088 + j],      bb1 = ws[1088 + 16 + j];
    const float bb2 = ws[1088 + 32 + j], bb3 = ws[1088 + 48 + j];

    const float* xrow = xs[g];
    float c = 0.0f, h = 0.0f;

    #pragma unroll 1
    for (int t = 0; t < TLEN; ++t) {
        const float xt = xrow[t];

        // h broadcast: 15 independent shuffles (depend only on h)
        const float hs1  = __shfl_xor(h, 1),  hs2  = __shfl_xor(h, 2);
        const float hs3  = __shfl_xor(h, 3),  hs4  = __shfl_xor(h, 4);
        const float hs5  = __shfl_xor(h, 5),  hs6  = __shfl_xor(h, 6);
        const float hs7  = __shfl_xor(h, 7),  hs8  = __shfl_xor(h, 8);
        const float hs9  = __shfl_xor(h, 9),  hs10 = __shfl_xor(h, 10);
        const float hs11 = __shfl_xor(h, 11), hs12 = __shfl_xor(h, 12);
        const float hs13 = __shfl_xor(h, 13), hs14 = __shfl_xor(h, 14);
        const float hs15 = __shfl_xor(h, 15);

        // 4 gate dot products, 2 accumulator chains each (depth 8)
        #define DOT16(A0, A1, W)                                     \
            A0 = fmaf(h,    W[0],  A0);  A1 = fmaf(hs1,  W[1],  A1); \
            A0 = fmaf(hs2,  W[2],  A0);  A1 = fmaf(hs3,  W[3],  A1); \
            A0 = fmaf(hs4,  W[4],  A0);  A1 = fmaf(hs5,  W[5],  A1); \
            A0 = fmaf(hs6,  W[6],  A0);  A1 = fmaf(hs7,  W[7],  A1); \
            A0 = fmaf(hs8,  W[8],  A0);  A1 = fmaf(hs9,  W[9],  A1); \
            A0 = fmaf(hs10, W[10], A0);  A1 = fmaf(hs11, W[11], A1); \
            A0 = fmaf(hs12, W[12], A0);  A1 = fmaf(hs13, W[13], A1); \
            A0 = fmaf(hs14, W[14], A0);  A1 = fmaf(hs15, W[15], A1);

        float aI0 = fmaf(xt, wi0, bb0), aI1 = 0.0f;
        float aF0 = fmaf(xt, wi1, bb1), aF1 = 0.0f;
        float aG0 = fmaf(xt, wi2, bb2), aG1 = 0.0f;
        float aO0 = fmaf(xt, wi3, bb3), aO1 = 0.0f;
        DOT16(aI0, aI1, w0)
        DOT16(aF0, aF1, w1)
        DOT16(aG0, aG1, w2)
        DOT16(aO0, aO1, w3)
        #undef DOT16

        const float accI = aI0 + aI1;
        const float accF = aF0 + aF1;
        const float accG = aG0 + aG1;
        const float accO = aO0 + aO1;

        // sigmoid(z) = rcp(1+exp2(-z*log2e)) -> weights pre-scaled; tanh = 2*sig(2z)-1
        const float gi = __builtin_amdgcn_rcpf(1.0f + __builtin_amdgcn_exp2f(accI));
        const float gf = __builtin_amdgcn_rcpf(1.0f + __builtin_amdgcn_exp2f(accF));
        const float gg = fmaf(2.0f, __builtin_amdgcn_rcpf(1.0f + __builtin_amdgcn_exp2f(accG)), -1.0f);
        const float go = __builtin_amdgcn_rcpf(1.0f + __builtin_amdgcn_exp2f(accO));

        c = fmaf(gf, c, gi * gg);
        const float th = fmaf(2.0f,
            __builtin_amdgcn_rcpf(1.0f + __builtin_amdgcn_exp2f(c * (-2.0f * LOG2E))), -1.0f);
        h = go * th;
    }

    // out[b] = sum_j h_j * W_lin[j] (16-lane reduce within the group)
    float v = h * W_lin[j];
    v += __shfl_xor(v, 1);
    v += __shfl_xor(v, 2);
    v += __shfl_xor(v, 4);
    v += __shfl_xor(v, 8);
    if (j == 0) out[blockIdx.x * 4 + g] = v;
}

extern "C" void kernel_launch(void* const* d_in, const int* in_sizes, int n_in,
                              void* d_out, int out_size, void* d_ws, size_t ws_size,
                              hipStream_t stream) {
    const float* x     = (const float*)d_in[0];
    const float* W_ih  = (const float*)d_in[1];
    const float* W_hh  = (const float*)d_in[2];
    const float* b_ih  = (const float*)d_in[3];
    const float* b_hh  = (const float*)d_in[4];
    const float* W_lin = (const float*)d_in[5];
    float* out = (float*)d_out;
    float* ws  = (float*)d_ws;

    const int B = in_sizes[0] / TLEN;  // 4096

    hipLaunchKernelGGL(prep_kernel, dim3(1), dim3(64), 0, stream,
                       W_ih, W_hh, b_ih, b_hh, ws);
    hipLaunchKernelGGL(lstm_kernel, dim3(B / 4), dim3(64), 0, stream,
                       x, ws, W_lin, out);
}

// Round 6
// 114.407 us; speedup vs baseline: 1.4036x; 1.2683x over previous
//
#include <hip/hip_runtime.h>

#define HSZ   16
#define TLEN  512
#define XPAD  4
#define LOG2E 1.4426950408889634f

// ws layout (floats): [0..1023] scaled W_hh [64][16]; [1024..1087] scaled W_ih; [1088..1151] scaled (b_ih+b_hh)
__global__ __launch_bounds__(64) void prep_kernel(
    const float* __restrict__ W_ih, const float* __restrict__ W_hh,
    const float* __restrict__ b_ih, const float* __restrict__ b_hh,
    float* __restrict__ ws)
{
    const int r = threadIdx.x;  // 0..63 gate row, torch order i,f,g,o
    const float s = (r >= 32 && r < 48) ? (-2.0f * LOG2E) : (-LOG2E);  // tanh rows get -2*log2e
    #pragma unroll
    for (int k = 0; k < HSZ; ++k) ws[r * HSZ + k] = s * W_hh[r * HSZ + k];
    ws[1024 + r] = s * W_ih[r];
    ws[1088 + r] = s * (b_ih[r] + b_hh[r]);
}

// DPP row-rotate within 16-lane rows (VALU pipe — no LDS). Direction is discovered at
// runtime via a lane-ID probe, so rotate-convention can't silently break correctness.
template<int N>
__device__ __forceinline__ int dpp_ror_i(int v) {
    return __builtin_amdgcn_update_dpp(v, v, 0x120 | N, 0xF, 0xF, false);
}
template<int N>
__device__ __forceinline__ float dpp_ror_f(float v) {
    return __int_as_float(dpp_ror_i<N>(__float_as_int(v)));
}

// 16 lanes per batch element; lane j owns gate rows {j,16+j,32+j,48+j}=(i,f,g,o)_j plus
// c_j,h_j. Gate math and the c/h update are lane-local; h broadcast = 15 DPP rotations
// paired with permutation-matched weights. 4 batches per wave, 1 wave per block.
__global__ __launch_bounds__(64) void lstm_kernel(
    const float* __restrict__ x, const float* __restrict__ ws,
    const float* __restrict__ W_lin, float* __restrict__ out)
{
    __shared__ __align__(16) float xs[4 * (TLEN + XPAD)];

    const int tid = threadIdx.x;
    const int g   = tid >> 4;   // batch slot within wave (0..3)
    const int j   = tid & 15;   // hidden index / lane within 16-lane group

    // stage x for 4 batches (coalesced float4 from global; padded rows in LDS)
    {
        const float4* xv = (const float4*)(x + (long)blockIdx.x * (4 * TLEN));
        #pragma unroll
        for (int b = 0; b < 4; ++b) {
            float4* dst = (float4*)(xs + b * (TLEN + XPAD));
            #pragma unroll
            for (int i = 0; i < 2; ++i)
                dst[i * 64 + tid] = xv[b * 128 + i * 64 + tid];
        }
    }
    __syncthreads();

    // discover the actual DPP source-lane map: src[m] = lane whose value term m delivers
    int src[16];
    src[0]  = j;
    src[1]  = dpp_ror_i<1>(j);   src[2]  = dpp_ror_i<2>(j);
    src[3]  = dpp_ror_i<3>(j);   src[4]  = dpp_ror_i<4>(j);
    src[5]  = dpp_ror_i<5>(j);   src[6]  = dpp_ror_i<6>(j);
    src[7]  = dpp_ror_i<7>(j);   src[8]  = dpp_ror_i<8>(j);
    src[9]  = dpp_ror_i<9>(j);   src[10] = dpp_ror_i<10>(j);
    src[11] = dpp_ror_i<11>(j);  src[12] = dpp_ror_i<12>(j);
    src[13] = dpp_ror_i<13>(j);  src[14] = dpp_ror_i<14>(j);
    src[15] = dpp_ror_i<15>(j);

    // permutation-matched scaled weights: term m multiplies h_{src[m]} by W[row][src[m]]
    float w0[16], w1[16], w2[16], w3[16];
    #pragma unroll
    for (int m = 0; m < 16; ++m) {
        const int k = src[m];
        w0[m] = ws[(     j) * HSZ + k];   // i row  (scaled -log2e)
        w1[m] = ws[(16 + j) * HSZ + k];   // f row
        w2[m] = ws[(32 + j) * HSZ + k];   // g row  (scaled -2log2e)
        w3[m] = ws[(48 + j) * HSZ + k];   // o row
    }
    const float wi0 = ws[1024 + j],      wi1 = ws[1024 + 16 + j];
    const float wi2 = ws[1024 + 32 + j], wi3 = ws[1024 + 48 + j];
    const float bb0 = ws[1088 + j],      bb1 = ws[1088 + 16 + j];
    const float bb2 = ws[1088 + 32 + j], bb3 = ws[1088 + 48 + j];

    const float* xrow = xs + g * (TLEN + XPAD);
    float c = 0.0f, h = 0.0f;

    #define STEP(XT) {                                                            \
        float hs[16];                                                             \
        hs[0]  = h;                                                               \
        hs[1]  = dpp_ror_f<1>(h);   hs[2]  = dpp_ror_f<2>(h);                     \
        hs[3]  = dpp_ror_f<3>(h);   hs[4]  = dpp_ror_f<4>(h);                     \
        hs[5]  = dpp_ror_f<5>(h);   hs[6]  = dpp_ror_f<6>(h);                     \
        hs[7]  = dpp_ror_f<7>(h);   hs[8]  = dpp_ror_f<8>(h);                     \
        hs[9]  = dpp_ror_f<9>(h);   hs[10] = dpp_ror_f<10>(h);                    \
        hs[11] = dpp_ror_f<11>(h);  hs[12] = dpp_ror_f<12>(h);                    \
        hs[13] = dpp_ror_f<13>(h);  hs[14] = dpp_ror_f<14>(h);                    \
        hs[15] = dpp_ror_f<15>(h);                                                \
        float aI0 = fmaf(XT, wi0, bb0), aI1 = 0.0f;                               \
        float aF0 = fmaf(XT, wi1, bb1), aF1 = 0.0f;                               \
        float aG0 = fmaf(XT, wi2, bb2), aG1 = 0.0f;                               \
        float aO0 = fmaf(XT, wi3, bb3), aO1 = 0.0f;                               \
        _Pragma("unroll")                                                         \
        for (int m = 0; m < 16; m += 2) {                                         \
            aI0 = fmaf(hs[m], w0[m], aI0);  aI1 = fmaf(hs[m+1], w0[m+1], aI1);    \
            aF0 = fmaf(hs[m], w1[m], aF0);  aF1 = fmaf(hs[m+1], w1[m+1], aF1);    \
            aG0 = fmaf(hs[m], w2[m], aG0);  aG1 = fmaf(hs[m+1], w2[m+1], aG1);    \
            aO0 = fmaf(hs[m], w3[m], aO0);  aO1 = fmaf(hs[m+1], w3[m+1], aO1);    \
        }                                                                         \
        const float gi = __builtin_amdgcn_rcpf(1.0f + __builtin_amdgcn_exp2f(aI0 + aI1)); \
        const float gf = __builtin_amdgcn_rcpf(1.0f + __builtin_amdgcn_exp2f(aF0 + aF1)); \
        const float gg = fmaf(2.0f, __builtin_amdgcn_rcpf(1.0f + __builtin_amdgcn_exp2f(aG0 + aG1)), -1.0f); \
        const float go = __builtin_amdgcn_rcpf(1.0f + __builtin_amdgcn_exp2f(aO0 + aO1)); \
        c = fmaf(gf, c, gi * gg);                                                 \
        const float th = fmaf(2.0f,                                               \
            __builtin_amdgcn_rcpf(1.0f + __builtin_amdgcn_exp2f(c * (-2.0f * LOG2E))), -1.0f); \
        h = go * th;                                                              \
    }

    #pragma unroll 1
    for (int t4 = 0; t4 < TLEN / 4; ++t4) {
        const float4 xq = *(const float4*)(xrow + 4 * t4);  // one LDS read per 4 steps
        STEP(xq.x)
        STEP(xq.y)
        STEP(xq.z)
        STEP(xq.w)
    }
    #undef STEP

    // out[b] = sum_j h_j * W_lin[j] (16-lane reduce within the group)
    float v = h * W_lin[j];
    v += __shfl_xor(v, 1);
    v += __shfl_xor(v, 2);
    v += __shfl_xor(v, 4);
    v += __shfl_xor(v, 8);
    if (j == 0) out[blockIdx.x * 4 + g] = v;
}

extern "C" void kernel_launch(void* const* d_in, const int* in_sizes, int n_in,
                              void* d_out, int out_size, void* d_ws, size_t ws_size,
                              hipStream_t stream) {
    const float* x     = (const float*)d_in[0];
    const float* W_ih  = (const float*)d_in[1];
    const float* W_hh  = (const float*)d_in[2];
    const float* b_ih  = (const float*)d_in[3];
    const float* b_hh  = (const float*)d_in[4];
    const float* W_lin = (const float*)d_in[5];
    float* out = (float*)d_out;
    float* ws  = (float*)d_ws;

    const int B = in_sizes[0] / TLEN;  // 4096

    hipLaunchKernelGGL(prep_kernel, dim3(1), dim3(64), 0, stream,
                       W_ih, W_hh, b_ih, b_hh, ws);
    hipLaunchKernelGGL(lstm_kernel, dim3(B / 4), dim3(64), 0, stream,
                       x, ws, W_lin, out);
}

// Round 7
// 91.487 us; speedup vs baseline: 1.7553x; 1.2505x over previous
//
#include <hip/hip_runtime.h>

#define HSZ   16
#define TLEN  512
#define XPAD  4
#define LOG2E 1.4426950408889634f

typedef _Float16 half2v __attribute__((ext_vector_type(2)));

// ws layout (floats): [0..1023] scaled W_hh [64][16]; [1024..1087] scaled W_ih; [1088..1151] scaled (b_ih+b_hh)
__global__ __launch_bounds__(64) void prep_kernel(
    const float* __restrict__ W_ih, const float* __restrict__ W_hh,
    const float* __restrict__ b_ih, const float* __restrict__ b_hh,
    float* __restrict__ ws)
{
    const int r = threadIdx.x;  // 0..63 gate row, torch order i,f,g,o
    const float s = (r >= 32 && r < 48) ? (-2.0f * LOG2E) : (-LOG2E);  // tanh rows get -2*log2e
    #pragma unroll
    for (int k = 0; k < HSZ; ++k) ws[r * HSZ + k] = s * W_hh[r * HSZ + k];
    ws[1024 + r] = s * W_ih[r];
    ws[1088 + r] = s * (b_ih[r] + b_hh[r]);
}

// DPP row-rotate within 16-lane rows (VALU pipe — no LDS). Lane maps are discovered at
// runtime via lane-ID probes, so the rotate convention can't silently break correctness.
template<int N>
__device__ __forceinline__ int dpp_ror_i(int v) {
    return __builtin_amdgcn_update_dpp(v, v, 0x120 | N, 0xF, 0xF, false);
}
template<int N>
__device__ __forceinline__ float dpp_ror_f(float v) {
    return __int_as_float(dpp_ror_i<N>(__float_as_int(v)));
}

// 16 lanes per batch element; lane j owns gate rows {j,16+j,32+j,48+j}=(i,f,g,o)_j plus
// c_j,h_j (all lane-local). h broadcast: pack (h, h_ror1) to half2 once, then 7 packed
// DPP rotations; matvec = 8 v_dot2_f32_f16 per gate with permutation-matched f16 weight
// pairs. Activations fused: gi*gg and go*tanh(c) each share one rcp. 4 batches/wave.
__global__ __launch_bounds__(64) void lstm_kernel(
    const float* __restrict__ x, const float* __restrict__ ws,
    const float* __restrict__ W_lin, float* __restrict__ out)
{
    __shared__ __align__(16) float xs[4 * (TLEN + XPAD)];

    const int tid = threadIdx.x;
    const int g   = tid >> 4;   // batch slot within wave (0..3)
    const int j   = tid & 15;   // hidden index / lane within 16-lane group

    // stage x for 4 batches (coalesced float4 from global; padded rows in LDS)
    {
        const float4* xv = (const float4*)(x + (long)blockIdx.x * (4 * TLEN));
        #pragma unroll
        for (int b = 0; b < 4; ++b) {
            float4* dst = (float4*)(xs + b * (TLEN + XPAD));
            #pragma unroll
            for (int i = 0; i < 2; ++i)
                dst[i * 64 + tid] = xv[b * 128 + i * 64 + tid];
        }
    }
    __syncthreads();

    // Discover DPP source-lane maps. P0 at lane j = (h[j], h[s1[j]]) where s1 = ror1 src.
    // Pm = ror<2m>(P0): lane j gets (h[lo_m[j]], h[hi_m[j]]), lo_m[j]=ror2m src,
    // hi_m[j]=s1 value AT that lane = dpp_ror<2m>(s1).
    const int s1 = dpp_ror_i<1>(j);
    int lo[8], hi[8];
    lo[0] = j;                  hi[0] = s1;
    lo[1] = dpp_ror_i<2>(j);    hi[1] = dpp_ror_i<2>(s1);
    lo[2] = dpp_ror_i<4>(j);    hi[2] = dpp_ror_i<4>(s1);
    lo[3] = dpp_ror_i<6>(j);    hi[3] = dpp_ror_i<6>(s1);
    lo[4] = dpp_ror_i<8>(j);    hi[4] = dpp_ror_i<8>(s1);
    lo[5] = dpp_ror_i<10>(j);   hi[5] = dpp_ror_i<10>(s1);
    lo[6] = dpp_ror_i<12>(j);   hi[6] = dpp_ror_i<12>(s1);
    lo[7] = dpp_ror_i<14>(j);   hi[7] = dpp_ror_i<14>(s1);

    // permutation-matched f16 weight pairs (RNE rounding via cast); scales baked in ws
    half2v wI[8], wF[8], wG[8], wO[8];
    #pragma unroll
    for (int m = 0; m < 8; ++m) {
        wI[m].x = (_Float16)ws[(     j) * HSZ + lo[m]];  wI[m].y = (_Float16)ws[(     j) * HSZ + hi[m]];
        wF[m].x = (_Float16)ws[(16 + j) * HSZ + lo[m]];  wF[m].y = (_Float16)ws[(16 + j) * HSZ + hi[m]];
        wG[m].x = (_Float16)ws[(32 + j) * HSZ + lo[m]];  wG[m].y = (_Float16)ws[(32 + j) * HSZ + hi[m]];
        wO[m].x = (_Float16)ws[(48 + j) * HSZ + lo[m]];  wO[m].y = (_Float16)ws[(48 + j) * HSZ + hi[m]];
    }
    const float wi0 = ws[1024 + j],      wi1 = ws[1024 + 16 + j];
    const float wi2 = ws[1024 + 32 + j], wi3 = ws[1024 + 48 + j];
    const float bb0 = ws[1088 + j],      bb1 = ws[1088 + 16 + j];
    const float bb2 = ws[1088 + 32 + j], bb3 = ws[1088 + 48 + j];

    const float* xrow = xs + g * (TLEN + XPAD);
    float c = 0.0f, h = 0.0f;

    #define STEP(XT) {                                                            \
        const float hr1 = dpp_ror_f<1>(h);                                        \
        half2v P0h; P0h.x = (_Float16)h; P0h.y = (_Float16)hr1;                   \
        const int q0 = __builtin_bit_cast(int, P0h);                              \
        const int q1 = dpp_ror_i<2>(q0),  q2 = dpp_ror_i<4>(q0);                  \
        const int q3 = dpp_ror_i<6>(q0),  q4 = dpp_ror_i<8>(q0);                  \
        const int q5 = dpp_ror_i<10>(q0), q6 = dpp_ror_i<12>(q0);                 \
        const int q7 = dpp_ror_i<14>(q0);                                         \
        const half2v P[8] = {                                                     \
            P0h,                          __builtin_bit_cast(half2v, q1),         \
            __builtin_bit_cast(half2v, q2), __builtin_bit_cast(half2v, q3),       \
            __builtin_bit_cast(half2v, q4), __builtin_bit_cast(half2v, q5),       \
            __builtin_bit_cast(half2v, q6), __builtin_bit_cast(half2v, q7) };     \
        float aI = fmaf(XT, wi0, bb0);                                            \
        float aF = fmaf(XT, wi1, bb1);                                            \
        float aG = fmaf(XT, wi2, bb2);                                            \
        float aO = fmaf(XT, wi3, bb3);                                            \
        _Pragma("unroll")                                                         \
        for (int m = 0; m < 8; ++m) {                                             \
            aI = __builtin_amdgcn_fdot2(P[m], wI[m], aI, false);                  \
            aF = __builtin_amdgcn_fdot2(P[m], wF[m], aF, false);                  \
            aG = __builtin_amdgcn_fdot2(P[m], wG[m], aG, false);                  \
            aO = __builtin_amdgcn_fdot2(P[m], wO[m], aO, false);                  \
        }                                                                         \
        const float eI = __builtin_amdgcn_exp2f(aI);   /* e^{-zi} */              \
        const float eF = __builtin_amdgcn_exp2f(aF);                              \
        const float eG = __builtin_amdgcn_exp2f(aG);   /* e^{-2zg} */             \
        const float eO = __builtin_amdgcn_exp2f(aO);                              \
        const float gf = __builtin_amdgcn_rcpf(1.0f + eF);                        \
        const float p  = (1.0f - eG) * __builtin_amdgcn_rcpf((1.0f + eI) * (1.0f + eG)); \
        c = fmaf(gf, c, p);                            /* f*c + i*tanh(g) */      \
        const float eC = __builtin_amdgcn_exp2f(c * (-2.0f * LOG2E));             \
        h = (1.0f - eC) * __builtin_amdgcn_rcpf((1.0f + eO) * (1.0f + eC));       \
    }

    #pragma unroll 1
    for (int t4 = 0; t4 < TLEN / 4; ++t4) {
        const float4 xq = *(const float4*)(xrow + 4 * t4);  // one LDS read per 4 steps
        STEP(xq.x)
        STEP(xq.y)
        STEP(xq.z)
        STEP(xq.w)
    }
    #undef STEP

    // out[b] = sum_j h_j * W_lin[j] (16-lane reduce within the group)
    float v = h * W_lin[j];
    v += __shfl_xor(v, 1);
    v += __shfl_xor(v, 2);
    v += __shfl_xor(v, 4);
    v += __shfl_xor(v, 8);
    if (j == 0) out[blockIdx.x * 4 + g] = v;
}

extern "C" void kernel_launch(void* const* d_in, const int* in_sizes, int n_in,
                              void* d_out, int out_size, void* d_ws, size_t ws_size,
                              hipStream_t stream) {
    const float* x     = (const float*)d_in[0];
    const float* W_ih  = (const float*)d_in[1];
    const float* W_hh  = (const float*)d_in[2];
    const float* b_ih  = (const float*)d_in[3];
    const float* b_hh  = (const float*)d_in[4];
    const float* W_lin = (const float*)d_in[5];
    float* out = (float*)d_out;
    float* ws  = (float*)d_ws;

    const int B = in_sizes[0] / TLEN;  // 4096

    hipLaunchKernelGGL(prep_kernel, dim3(1), dim3(64), 0, stream,
                       W_ih, W_hh, b_ih, b_hh, ws);
    hipLaunchKernelGGL(lstm_kernel, dim3(B / 4), dim3(64), 0, stream,
                       x, ws, W_lin, out);
}